// Round 1
// baseline (2305.271 us; speedup 1.0000x reference)
//
#include <hip/hip_runtime.h>
#include <hip/hip_bf16.h>

// Problem constants
#define H_    128
#define IN_   93
#define NL_   4
#define B_    256
#define T_    512
#define G_    512   // 4*H
#define LOG2E 1.44269504088896f

typedef __attribute__((ext_vector_type(8))) short bf16x8;
typedef __attribute__((ext_vector_type(4))) float f32x4;

__device__ __forceinline__ ushort bf16_rn(float f) {
    uint x = __float_as_uint(f);
    uint r = (x + 0x7FFFu + ((x >> 16) & 1u)) >> 16;
    return (ushort)r;
}

__device__ __forceinline__ float exp2_fast(float x) {
    return __builtin_amdgcn_exp2f(x);
}
__device__ __forceinline__ float rcp_fast(float x) {
    return __builtin_amdgcn_rcpf(x);
}
// y is pre-scaled by log2e: sigmoid(x) with y = x*log2e
__device__ __forceinline__ float sig_y(float y) {
    return rcp_fast(1.0f + exp2_fast(-y));
}
// y is pre-scaled by 2*log2e: tanh(x) with y = 2*log2e*x
__device__ __forceinline__ float tanh_y(float y) {
    return __builtin_fmaf(2.0f, rcp_fast(1.0f + exp2_fast(-y)), -1.0f);
}

// ---------------------------------------------------------------------------
// prep_x: x [B][T][93] f32  ->  xb [T][B][96] bf16 (zero-padded 93..95)
// ---------------------------------------------------------------------------
__global__ void prep_x(const float* __restrict__ x, ushort* __restrict__ xb) {
    int idx = blockIdx.x * 256 + threadIdx.x;   // < T*B*96 = 12,582,912
    int t = idx / (B_ * 96);
    int rem = idx % (B_ * 96);
    int b = rem / 96;
    int k = rem % 96;
    float v = 0.0f;
    if (k < IN_) v = x[((size_t)b * T_ + t) * IN_ + k];
    xb[idx] = bf16_rn(v);
}

// ---------------------------------------------------------------------------
// prep_w: build combined prescaled bf16 weights Wc [NL][512][256]
//   cols [0,Kx)        : W_ih (layer0: 93 real + 3 zero)
//   cols [Kx, Kx+128)  : W_hh
//   rest               : 0
// rows (gates) scaled by log2e (i,f,o) or 2*log2e (g: rows 256..383)
// ---------------------------------------------------------------------------
__global__ void prep_w(const float* __restrict__ Wih0,
                       const float* __restrict__ Wihr,
                       const float* __restrict__ Whh,
                       ushort* __restrict__ Wc) {
    int idx = blockIdx.x * 256 + threadIdx.x;   // < 4*512*256 = 524,288
    int l = idx / (G_ * 256);
    int rem = idx % (G_ * 256);
    int g = rem / 256;
    int k = rem % 256;
    int kx = (l == 0) ? 96 : 128;
    float v = 0.0f;
    if (k < kx) {
        if (l == 0) {
            if (k < IN_) v = Wih0[g * IN_ + k];
        } else {
            v = Wihr[(((size_t)(l - 1)) * G_ + g) * H_ + k];
        }
    } else if (k < kx + H_) {
        v = Whh[(((size_t)l) * G_ + g) * H_ + (k - kx)];
    }
    float scale = (g >= 256 && g < 384) ? (2.0f * LOG2E) : LOG2E;
    Wc[idx] = bf16_rn(v * scale);
}

// ---------------------------------------------------------------------------
// prep_bias: bias_c [NL][512] = (b_ih + b_hh) * scale
// ---------------------------------------------------------------------------
__global__ void prep_bias(const float* __restrict__ bih,
                          const float* __restrict__ bhh,
                          float* __restrict__ bc) {
    int idx = blockIdx.x * 256 + threadIdx.x;   // < 2048
    int g = idx & 511;
    float scale = (g >= 256 && g < 384) ? (2.0f * LOG2E) : LOG2E;
    bc[idx] = (bih[idx] + bhh[idx]) * scale;
}

// ---------------------------------------------------------------------------
// recur_kernel: one LSTM layer, full T loop.
// 16 blocks x 512 threads (8 waves). Block owns batch rows b0..b0+15.
// Wave w owns units 16w..16w+15 via 4 gate tiles (i,f,g,o).
// Weights persistent in VGPRs; h persistent in LDS; c persistent in VGPRs.
// src: prev-layer h (or xb), stride kx, bf16.  hg: this layer h out (in-place ok).
// ---------------------------------------------------------------------------
__global__ __launch_bounds__(512, 2)
void recur_kernel(const ushort* __restrict__ src, int kx,
                  const ushort* __restrict__ Wc,
                  const float* __restrict__ bias,
                  ushort* __restrict__ hg) {
    __shared__ ushort comb[16][272];   // cols [0,kx)=x, [kx,kx+128)=h, rest 0

    const int tid = threadIdx.x;
    const int w   = tid >> 6;          // wave 0..7
    const int ln  = tid & 63;
    const int q   = ln >> 4;           // 0..3 (row-quad)
    const int lo  = ln & 15;           // A-row / unit-col within tile
    const int u   = (w << 4) | lo;     // unit 0..127
    const int b0  = blockIdx.x << 4;

    // zero LDS (h starts at 0; cols beyond kx+128 stay 0 forever)
    for (int i = tid; i < 16 * 272; i += 512) ((ushort*)comb)[i] = 0;

    // persistent B fragments: bw[gate_type][kstep]
    bf16x8 bw[4][8];
#pragma unroll
    for (int tu = 0; tu < 4; ++tu) {
#pragma unroll
        for (int s = 0; s < 8; ++s) {
            const ushort* p = Wc + ((size_t)((tu << 7) + u) << 8) + (s << 5) + (q << 3);
            bw[tu][s] = *(const bf16x8*)p;
        }
    }

    float bv0 = bias[u];
    float bv1 = bias[128 + u];
    float bv2 = bias[256 + u];
    float bv3 = bias[384 + u];

    f32x4 cc = {0.0f, 0.0f, 0.0f, 0.0f};

    // staging assignment: thread -> (row, 8-byte segment)
    const int srow = tid >> 5;         // 0..15
    const int seg  = tid & 31;         // 0..31
    const int nseg = kx >> 2;          // 24 or 32
    const bool act = (seg < nseg);

    uint2 xr = {0u, 0u};
    if (act) xr = *(const uint2*)(src + (size_t)(b0 + srow) * kx + (seg << 2));

    __syncthreads();   // LDS zero visible

    for (int t = 0; t < T_; ++t) {
        // write staged x for this step
        if (act) *(uint2*)&comb[srow][seg << 2] = xr;
        // prefetch next step's x (hidden under MFMAs)
        uint2 xr2 = {0u, 0u};
        if (act && t < T_ - 1)
            xr2 = *(const uint2*)(src + (size_t)((t + 1) * B_ + b0 + srow) * kx + (seg << 2));
        __syncthreads();   // x staged + prev h writes visible

        f32x4 a0 = {bv0, bv0, bv0, bv0};
        f32x4 a1 = {bv1, bv1, bv1, bv1};
        f32x4 a2 = {bv2, bv2, bv2, bv2};
        f32x4 a3 = {bv3, bv3, bv3, bv3};
#pragma unroll
        for (int s = 0; s < 8; ++s) {
            bf16x8 av = *(const bf16x8*)&comb[lo][(s << 5) + (q << 3)];
            a0 = __builtin_amdgcn_mfma_f32_16x16x32_bf16(av, bw[0][s], a0, 0, 0, 0);
            a1 = __builtin_amdgcn_mfma_f32_16x16x32_bf16(av, bw[1][s], a1, 0, 0, 0);
            a2 = __builtin_amdgcn_mfma_f32_16x16x32_bf16(av, bw[2][s], a2, 0, 0, 0);
            a3 = __builtin_amdgcn_mfma_f32_16x16x32_bf16(av, bw[3][s], a3, 0, 0, 0);
        }
        __syncthreads();   // all A-reads done before h is overwritten

        // epilogue: lane holds i,f,g,o for unit u, rows 4q..4q+3
#pragma unroll
        for (int r = 0; r < 4; ++r) {
            float i_ = sig_y(a0[r]);
            float f_ = sig_y(a1[r]);
            float g_ = tanh_y(a2[r]);
            float o_ = sig_y(a3[r]);
            float cn = __builtin_fmaf(f_, cc[r], i_ * g_);
            cc[r] = cn;
            float th = tanh_y(2.88539008177793f * cn);
            float h_ = o_ * th;
            ushort hb = bf16_rn(h_);
            int row = (q << 2) + r;
            comb[row][kx + u] = hb;
            hg[(size_t)(t * B_ + b0 + row) * H_ + u] = hb;
        }
        xr = xr2;
    }
}

// ---------------------------------------------------------------------------
// fc_kernel: out[b*T + t] = sigmoid( dot(h3[t][b][:], wfc) + bfc )
// one block per t, one thread per b
// ---------------------------------------------------------------------------
__global__ void fc_kernel(const ushort* __restrict__ hg,
                          const float* __restrict__ wfc,
                          const float* __restrict__ bfc,
                          float* __restrict__ out) {
    int t = blockIdx.x;
    int b = threadIdx.x;
    const uint4* hr = (const uint4*)(hg + (size_t)(t * B_ + b) * H_);
    float acc = 0.0f;
#pragma unroll
    for (int kk = 0; kk < 16; ++kk) {
        uint4 p = hr[kk];
        const uint vv[4] = {p.x, p.y, p.z, p.w};
#pragma unroll
        for (int j = 0; j < 4; ++j) {
            float f0 = __uint_as_float(vv[j] << 16);
            float f1 = __uint_as_float(vv[j] & 0xFFFF0000u);
            acc = __builtin_fmaf(f0, wfc[kk * 8 + j * 2 + 0], acc);
            acc = __builtin_fmaf(f1, wfc[kk * 8 + j * 2 + 1], acc);
        }
    }
    float z = acc + bfc[0];
    out[(size_t)b * T_ + t] = rcp_fast(1.0f + exp2_fast(-z * LOG2E));
}

// ---------------------------------------------------------------------------
extern "C" void kernel_launch(void* const* d_in, const int* in_sizes, int n_in,
                              void* d_out, int out_size, void* d_ws, size_t ws_size,
                              hipStream_t stream) {
    const float* x    = (const float*)d_in[0];
    const float* Wih0 = (const float*)d_in[1];
    const float* Wihr = (const float*)d_in[2];
    const float* Whh  = (const float*)d_in[3];
    const float* bih  = (const float*)d_in[4];
    const float* bhh  = (const float*)d_in[5];
    const float* Wfc  = (const float*)d_in[6];
    const float* bfc  = (const float*)d_in[7];
    float* out = (float*)d_out;

    char* ws = (char*)d_ws;
    const size_t xb_bytes   = (size_t)T_ * B_ * 96 * 2;       // 25,165,824
    const size_t wc_bytes   = (size_t)NL_ * G_ * 256 * 2;     //  1,048,576
    const size_t bias_bytes = (size_t)NL_ * G_ * 4;           //      8,192
    ushort* xb    = (ushort*)ws;
    ushort* Wc    = (ushort*)(ws + xb_bytes);
    float*  biasc = (float*)(ws + xb_bytes + wc_bytes);
    ushort* hgbuf = (ushort*)(ws + xb_bytes + wc_bytes + bias_bytes);

    prep_x<<<(T_ * B_ * 96) / 256, 256, 0, stream>>>(x, xb);
    prep_w<<<(NL_ * G_ * 256) / 256, 256, 0, stream>>>(Wih0, Wihr, Whh, Wc);
    prep_bias<<<(NL_ * G_) / 256, 256, 0, stream>>>(bih, bhh, biasc);

    // layer 0: input = xb (kx=96)
    recur_kernel<<<16, 512, 0, stream>>>(xb, 96, Wc, biasc, hgbuf);
    // layers 1..3: input = h (in-place), kx=128
    for (int l = 1; l < NL_; ++l) {
        recur_kernel<<<16, 512, 0, stream>>>(hgbuf, 128,
                                             Wc + (size_t)l * G_ * 256,
                                             biasc + (size_t)l * G_,
                                             hgbuf);
    }
    fc_kernel<<<T_, B_, 0, stream>>>(hgbuf, Wfc, bfc, out);
}

// Round 2
// 987.484 us; speedup vs baseline: 2.3345x; 2.3345x over previous
//
#include <hip/hip_runtime.h>
#include <hip/hip_bf16.h>

// Problem constants
#define H_    128
#define IN_   93
#define NL_   4
#define B_    256
#define T_    512
#define G_    512   // 4*H
#define W_    32    // inter-layer ring depth (steps), power of 2
#define LOG2E 1.44269504088896f

typedef __attribute__((ext_vector_type(8))) short bf16x8;
typedef __attribute__((ext_vector_type(4))) float f32x4;
typedef unsigned long long u64;

#define RING_SLOT (H_ * B_)          // 32768 elems per slot ([u][b])
#define RING_L    ((size_t)W_ * RING_SLOT)

__device__ __forceinline__ ushort bf16_rn(float f) {
    uint x = __float_as_uint(f);
    uint r = (x + 0x7FFFu + ((x >> 16) & 1u)) >> 16;
    return (ushort)r;
}
__device__ __forceinline__ float exp2_fast(float x) { return __builtin_amdgcn_exp2f(x); }
__device__ __forceinline__ float rcp_fast(float x)  { return __builtin_amdgcn_rcpf(x); }
// y pre-scaled by log2e
__device__ __forceinline__ float sig_y(float y)  { return rcp_fast(1.0f + exp2_fast(-y)); }
// y pre-scaled by 2*log2e
__device__ __forceinline__ float tanh_y(float y) { return __builtin_fmaf(2.0f, rcp_fast(1.0f + exp2_fast(-y)), -1.0f); }

__device__ __forceinline__ int spin_ge(int* p, int target) {
    int v = __hip_atomic_load(p, __ATOMIC_ACQUIRE, __HIP_MEMORY_SCOPE_AGENT);
    while (v < target) {
        __builtin_amdgcn_s_sleep(8);
        v = __hip_atomic_load(p, __ATOMIC_ACQUIRE, __HIP_MEMORY_SCOPE_AGENT);
    }
    return v;
}

// ---------------------------------------------------------------------------
// prep_x: x [B][T][93] f32 -> xb [T][B][96] bf16 (zero-padded)
// ---------------------------------------------------------------------------
__global__ void prep_x(const float* __restrict__ x, ushort* __restrict__ xb) {
    int idx = blockIdx.x * 256 + threadIdx.x;
    int t = idx / (B_ * 96);
    int rem = idx % (B_ * 96);
    int b = rem / 96;
    int k = rem % 96;
    float v = 0.0f;
    if (k < IN_) v = x[((size_t)b * T_ + t) * IN_ + k];
    xb[idx] = bf16_rn(v);
}

// ---------------------------------------------------------------------------
// prep_w: combined prescaled bf16 weights Wc [NL][512][256]
// ---------------------------------------------------------------------------
__global__ void prep_w(const float* __restrict__ Wih0,
                       const float* __restrict__ Wihr,
                       const float* __restrict__ Whh,
                       ushort* __restrict__ Wc) {
    int idx = blockIdx.x * 256 + threadIdx.x;
    int l = idx / (G_ * 256);
    int rem = idx % (G_ * 256);
    int g = rem / 256;
    int k = rem % 256;
    int kx = (l == 0) ? 96 : 128;
    float v = 0.0f;
    if (k < kx) {
        if (l == 0) { if (k < IN_) v = Wih0[g * IN_ + k]; }
        else        { v = Wihr[(((size_t)(l - 1)) * G_ + g) * H_ + k]; }
    } else if (k < kx + H_) {
        v = Whh[(((size_t)l) * G_ + g) * H_ + (k - kx)];
    }
    float scale = (g >= 256 && g < 384) ? (2.0f * LOG2E) : LOG2E;
    Wc[idx] = bf16_rn(v * scale);
}

__global__ void prep_bias(const float* __restrict__ bih,
                          const float* __restrict__ bhh,
                          float* __restrict__ bc) {
    int idx = blockIdx.x * 256 + threadIdx.x;
    int g = idx & 511;
    float scale = (g >= 256 && g < 384) ? (2.0f * LOG2E) : LOG2E;
    bc[idx] = (bih[idx] + bhh[idx]) * scale;
}

__global__ void zero_prog(int* __restrict__ prog) {
    int i = threadIdx.x;
    for (int k = i; k < NL_ * 16 * 16; k += 256) prog[k] = 0;
}

// ---------------------------------------------------------------------------
// recur_all: all 4 layers pipelined. grid = 64 blocks: blockIdx = l*16 + g
// (XCD = blockIdx%8 = g%8 -> the 4 layers of a group co-locate on one XCD).
// Block = 512 threads (8 waves); wave w owns units 16w..16w+15 (4 gate tiles).
// Ping-pong LDS [x|h] tile; ONE barrier per step.
// Inter-layer: bf16 ring [l][t%W][u][b] with sc1 atomics + prog counters.
// ---------------------------------------------------------------------------
__global__ __launch_bounds__(512, 2)
void recur_all(const ushort* __restrict__ xb,
               const ushort* __restrict__ Wc,
               const float* __restrict__ biasc,
               ushort* __restrict__ ring,
               ushort* __restrict__ h3,
               int* __restrict__ prog) {
    __shared__ ushort comb[2][16][272];

    const int bid = blockIdx.x;
    const int l = bid >> 4;
    const int g = bid & 15;
    const int kx = (l == 0) ? 96 : 128;

    const int tid = threadIdx.x;
    const int w   = tid >> 6;
    const int ln  = tid & 63;
    const int q   = ln >> 4;
    const int lo  = ln & 15;
    const int u   = (w << 4) | lo;
    const int b0  = g << 4;

    const ushort* Wl = Wc + (size_t)l * G_ * 256;
    const float*  bl = biasc + l * G_;
    int* prog_self = prog + (l * 16 + g) * 16;
    int* prog_up   = prog + ((l - 1) * 16 + g) * 16;   // valid if l>0
    int* prog_down = prog + ((l + 1) * 16 + g) * 16;   // valid if l<3

    // zero both LDS buffers (h_{-1}=0; pad cols stay 0)
    for (int i = tid; i < 2 * 16 * 272; i += 512) ((ushort*)comb)[i] = 0;

    // persistent B fragments
    bf16x8 bw[4][8];
#pragma unroll
    for (int tu = 0; tu < 4; ++tu)
#pragma unroll
        for (int s = 0; s < 8; ++s) {
            const ushort* pp = Wl + ((size_t)((tu << 7) + u) << 8) + (s << 5) + (q << 3);
            bw[tu][s] = *(const bf16x8*)pp;
        }

    const float bv0 = bl[u];
    const float bv1 = bl[128 + u];
    const float bv2 = bl[256 + u];
    const float bv3 = bl[384 + u];

    f32x4 cc = {0.0f, 0.0f, 0.0f, 0.0f};

    // layer-0 staging map
    const int srow = tid >> 5;
    const int seg  = tid & 31;
    const bool act = (seg < 24);           // 24*4 = 96 cols
    // consumer staging map
    const int uu = tid >> 2;               // 0..127
    const int r4 = (tid & 3) << 2;         // 0,4,8,12

    uint2 xr = {0u, 0u};
    u64 hx = 0;
    int avail = 0;

    // preload x_0
    if (l == 0) {
        if (act) xr = *(const uint2*)(xb + (size_t)(b0 + srow) * 96 + (seg << 2));
    } else {
        avail = spin_ge(prog_up, 1);
        const u64* sp = (const u64*)(ring + (size_t)(l - 1) * RING_L + (size_t)uu * B_ + (b0 + r4));
        hx = __hip_atomic_load((u64*)sp, __ATOMIC_RELAXED, __HIP_MEMORY_SCOPE_AGENT);
    }

    __syncthreads();   // LDS zero visible

    for (int t = 0; t < T_; ++t) {
        const int p = t & 1;

        // A: write staged x_t into comb[p] (h-part was written by prev epilogue)
        if (l == 0) {
            if (act) *(uint2*)&comb[p][srow][seg << 2] = xr;
        } else {
#pragma unroll
            for (int j = 0; j < 4; ++j)
                comb[p][r4 + j][uu] = (ushort)(hx >> (16 * j));
        }

        __syncthreads();   // everything for step t staged; h_{t-1} stores drained

        // publish progress (h_{t-1} is globally visible: sc1 stores + vmcnt drain)
        if (tid == 0 && t > 0)
            __hip_atomic_store(prog_self, t, __ATOMIC_RELAXED, __HIP_MEMORY_SCOPE_AGENT);
        // producer back-pressure (ring reuse), checked every 16 steps
        if (l < 3 && t >= W_ && (t & 15) == 0)
            (void)spin_ge(prog_down, t - 16);

        // B: prefetch x_{t+1} (after barrier so it overlaps MFMA+epilogue)
        if (t < T_ - 1) {
            if (l == 0) {
                if (act) xr = *(const uint2*)(xb + (size_t)((t + 1) * B_ + b0 + srow) * 96 + (seg << 2));
            } else {
                if (avail < t + 2) {
                    int tgt = t + 8; if (tgt > T_) tgt = T_;
                    avail = spin_ge(prog_up, tgt);
                }
                const u64* sp = (const u64*)(ring + (size_t)(l - 1) * RING_L +
                                             (size_t)((t + 1) & (W_ - 1)) * RING_SLOT +
                                             (size_t)uu * B_ + (b0 + r4));
                hx = __hip_atomic_load((u64*)sp, __ATOMIC_RELAXED, __HIP_MEMORY_SCOPE_AGENT);
            }
        }

        // E: gates = [x|h] . W^T  (M=16 rows, 4 gate tiles, K=256)
        f32x4 a0 = {bv0, bv0, bv0, bv0};
        f32x4 a1 = {bv1, bv1, bv1, bv1};
        f32x4 a2 = {bv2, bv2, bv2, bv2};
        f32x4 a3 = {bv3, bv3, bv3, bv3};
#pragma unroll
        for (int s = 0; s < 8; ++s) {
            bf16x8 av = *(const bf16x8*)&comb[p][lo][(s << 5) + (q << 3)];
            a0 = __builtin_amdgcn_mfma_f32_16x16x32_bf16(av, bw[0][s], a0, 0, 0, 0);
            a1 = __builtin_amdgcn_mfma_f32_16x16x32_bf16(av, bw[1][s], a1, 0, 0, 0);
            a2 = __builtin_amdgcn_mfma_f32_16x16x32_bf16(av, bw[2][s], a2, 0, 0, 0);
            a3 = __builtin_amdgcn_mfma_f32_16x16x32_bf16(av, bw[3][s], a3, 0, 0, 0);
        }

        // F: cell update; h_t -> comb[p^1] (read by step t+1) + global
        u64 hv = 0;
#pragma unroll
        for (int r = 0; r < 4; ++r) {
            float i_ = sig_y(a0[r]);
            float f_ = sig_y(a1[r]);
            float g_ = tanh_y(a2[r]);
            float o_ = sig_y(a3[r]);
            float cn = __builtin_fmaf(f_, cc[r], i_ * g_);
            cc[r] = cn;
            float th = tanh_y(2.88539008177793f * cn);
            float h_ = o_ * th;
            ushort hb = bf16_rn(h_);
            comb[p ^ 1][(q << 2) + r][kx + u] = hb;
            hv |= (u64)hb << (16 * r);
        }
        if (l < 3) {
            u64* dst = (u64*)(ring + (size_t)l * RING_L +
                              (size_t)(t & (W_ - 1)) * RING_SLOT +
                              (size_t)u * B_ + (b0 + (q << 2)));
            __hip_atomic_store(dst, hv, __ATOMIC_RELAXED, __HIP_MEMORY_SCOPE_AGENT);
        } else {
            *(u64*)(h3 + (size_t)t * RING_SLOT + (size_t)u * B_ + (b0 + (q << 2))) = hv;
        }
    }

    __syncthreads();   // drain final h stores
    if (tid == 0)
        __hip_atomic_store(prog_self, T_, __ATOMIC_RELAXED, __HIP_MEMORY_SCOPE_AGENT);
}

// ---------------------------------------------------------------------------
// fc: out[b*T+t] = sigmoid( dot(h3[t][:][b], wfc) + bfc ); h3 layout [t][u][b]
// ---------------------------------------------------------------------------
__global__ void fc_kernel(const ushort* __restrict__ h3,
                          const float* __restrict__ wfc,
                          const float* __restrict__ bfc,
                          float* __restrict__ out) {
    int t = blockIdx.x;
    int b = threadIdx.x;
    const ushort* hp = h3 + (size_t)t * RING_SLOT + b;
    float acc = 0.0f;
#pragma unroll 8
    for (int u = 0; u < H_; ++u) {
        float hv = __uint_as_float(((uint)hp[(size_t)u * B_]) << 16);
        acc = __builtin_fmaf(hv, wfc[u], acc);
    }
    float z = acc + bfc[0];
    out[(size_t)b * T_ + t] = rcp_fast(1.0f + exp2_fast(-z * LOG2E));
}

// ---------------------------------------------------------------------------
extern "C" void kernel_launch(void* const* d_in, const int* in_sizes, int n_in,
                              void* d_out, int out_size, void* d_ws, size_t ws_size,
                              hipStream_t stream) {
    const float* x    = (const float*)d_in[0];
    const float* Wih0 = (const float*)d_in[1];
    const float* Wihr = (const float*)d_in[2];
    const float* Whh  = (const float*)d_in[3];
    const float* bih  = (const float*)d_in[4];
    const float* bhh  = (const float*)d_in[5];
    const float* Wfc  = (const float*)d_in[6];
    const float* bfc  = (const float*)d_in[7];
    float* out = (float*)d_out;

    char* ws = (char*)d_ws;
    const size_t xb_bytes   = (size_t)T_ * B_ * 96 * 2;           // 25,165,824
    const size_t wc_bytes   = (size_t)NL_ * G_ * 256 * 2;         //  1,048,576
    const size_t bias_bytes = (size_t)NL_ * G_ * 4;               //      8,192
    const size_t prog_bytes = (size_t)NL_ * 16 * 16 * 4;          //      4,096
    const size_t ring_bytes = (size_t)3 * RING_L * 2;             //  6,291,456

    ushort* xb    = (ushort*)ws;
    ushort* Wc    = (ushort*)(ws + xb_bytes);
    float*  biasc = (float*)(ws + xb_bytes + wc_bytes);
    int*    prog  = (int*)(ws + xb_bytes + wc_bytes + bias_bytes);
    ushort* ring  = (ushort*)(ws + xb_bytes + wc_bytes + bias_bytes + prog_bytes);
    ushort* h3    = (ushort*)(ws + xb_bytes + wc_bytes + bias_bytes + prog_bytes + ring_bytes);

    prep_x<<<(T_ * B_ * 96) / 256, 256, 0, stream>>>(x, xb);
    prep_w<<<(NL_ * G_ * 256) / 256, 256, 0, stream>>>(Wih0, Wihr, Whh, Wc);
    prep_bias<<<(NL_ * G_) / 256, 256, 0, stream>>>(bih, bhh, biasc);
    zero_prog<<<1, 256, 0, stream>>>(prog);

    recur_all<<<NL_ * 16, 512, 0, stream>>>(xb, Wc, biasc, ring, h3, prog);

    fc_kernel<<<T_, B_, 0, stream>>>(h3, Wfc, bfc, out);
}

// Round 3
// 976.447 us; speedup vs baseline: 2.3609x; 1.0113x over previous
//
#include <hip/hip_runtime.h>
#include <hip/hip_bf16.h>

// Problem constants
#define H_    128
#define IN_   93
#define NL_   4
#define B_    256
#define T_    512
#define G_    512   // 4*H
#define W_    32    // inter-layer ring depth (steps), power of 2
#define LOG2E 1.44269504088896f

typedef __attribute__((ext_vector_type(8))) short bf16x8;
typedef __attribute__((ext_vector_type(4))) float f32x4;
typedef unsigned long long u64;

#define RING_SLOT (B_ * H_)          // 32768 elems per slot, layout [b][u]
#define RING_L    ((size_t)W_ * RING_SLOT)

__device__ __forceinline__ ushort bf16_rn(float f) {
    uint x = __float_as_uint(f);
    uint r = (x + 0x7FFFu + ((x >> 16) & 1u)) >> 16;
    return (ushort)r;
}
__device__ __forceinline__ float exp2_fast(float x) { return __builtin_amdgcn_exp2f(x); }
__device__ __forceinline__ float rcp_fast(float x)  { return __builtin_amdgcn_rcpf(x); }

__device__ __forceinline__ int spin_ge(int* p, int target) {
    int v = __hip_atomic_load(p, __ATOMIC_ACQUIRE, __HIP_MEMORY_SCOPE_AGENT);
    while (v < target) {
        __builtin_amdgcn_s_sleep(2);
        v = __hip_atomic_load(p, __ATOMIC_ACQUIRE, __HIP_MEMORY_SCOPE_AGENT);
    }
    return v;
}

// ---------------------------------------------------------------------------
// prep_x: x [B][T][93] f32 -> xb [T][B][96] bf16 (zero-padded)
// ---------------------------------------------------------------------------
__global__ void prep_x(const float* __restrict__ x, ushort* __restrict__ xb) {
    int idx = blockIdx.x * 256 + threadIdx.x;
    int t = idx / (B_ * 96);
    int rem = idx % (B_ * 96);
    int b = rem / 96;
    int k = rem % 96;
    float v = 0.0f;
    if (k < IN_) v = x[((size_t)b * T_ + t) * IN_ + k];
    xb[idx] = bf16_rn(v);
}

// ---------------------------------------------------------------------------
// prep_w: combined prescaled bf16 weights Wc [NL][512][256]
// ---------------------------------------------------------------------------
__global__ void prep_w(const float* __restrict__ Wih0,
                       const float* __restrict__ Wihr,
                       const float* __restrict__ Whh,
                       ushort* __restrict__ Wc) {
    int idx = blockIdx.x * 256 + threadIdx.x;
    int l = idx / (G_ * 256);
    int rem = idx % (G_ * 256);
    int g = rem / 256;
    int k = rem % 256;
    int kx = (l == 0) ? 96 : 128;
    float v = 0.0f;
    if (k < kx) {
        if (l == 0) { if (k < IN_) v = Wih0[g * IN_ + k]; }
        else        { v = Wihr[(((size_t)(l - 1)) * G_ + g) * H_ + k]; }
    } else if (k < kx + H_) {
        v = Whh[(((size_t)l) * G_ + g) * H_ + (k - kx)];
    }
    float scale = (g >= 256 && g < 384) ? (2.0f * LOG2E) : LOG2E;
    Wc[idx] = bf16_rn(v * scale);
}

__global__ void prep_bias(const float* __restrict__ bih,
                          const float* __restrict__ bhh,
                          float* __restrict__ bc) {
    int idx = blockIdx.x * 256 + threadIdx.x;
    int g = idx & 511;
    float scale = (g >= 256 && g < 384) ? (2.0f * LOG2E) : LOG2E;
    bc[idx] = (bih[idx] + bhh[idx]) * scale;
}

__global__ void zero_prog(int* __restrict__ prog) {
    int i = threadIdx.x;
    for (int k = i; k < NL_ * 16 * 16; k += 256) prog[k] = 0;
}

// ---------------------------------------------------------------------------
// recur_all: all 4 layers pipelined. grid = 64 blocks: blockIdx = l*16 + g.
// Per step: A(stage LDS) -> barrier -> C(ALL global ops issue here: store
// h_{t-1} from LDS coalesced, publish, back-pressure, prefetch h_{t+1})
// -> D(MFMA) -> E(cell update, h_t -> LDS only).
// Every global op gets the full D+E phase of slack before the next barrier's
// vmcnt(0) drain -> latency off the critical path.
// Ring layout [l][t%W][b][u]: 512B contiguous per wave on both sides.
// ---------------------------------------------------------------------------
__global__ __launch_bounds__(512, 2)
void recur_all(const ushort* __restrict__ xb,
               const ushort* __restrict__ Wc,
               const float* __restrict__ biasc,
               ushort* __restrict__ ring,
               ushort* __restrict__ h3,
               int* __restrict__ prog) {
    __shared__ ushort comb[2][16][272];

    const int bid = blockIdx.x;
    const int l = bid >> 4;
    const int g = bid & 15;
    const int kx = (l == 0) ? 96 : 128;

    const int tid = threadIdx.x;
    const int w   = tid >> 6;
    const int ln  = tid & 63;
    const int q   = ln >> 4;
    const int lo  = ln & 15;
    const int u   = (w << 4) | lo;
    const int b0  = g << 4;

    const ushort* Wl = Wc + (size_t)l * G_ * 256;
    const float*  bl = biasc + l * G_;
    int* prog_self = prog + (l * 16 + g) * 16;
    int* prog_up   = prog + ((l - 1) * 16 + g) * 16;   // valid if l>0
    int* prog_down = prog + ((l + 1) * 16 + g) * 16;   // valid if l<3

    ushort* ring_self = ring + (size_t)l * RING_L;            // producer (l<3)
    const ushort* ring_up = ring + (size_t)(l - 1) * RING_L;  // consumer (l>0)

    // zero both LDS buffers (h_{-1}=0; pad cols stay 0)
    for (int i = tid; i < 2 * 16 * 272; i += 512) ((ushort*)comb)[i] = 0;

    // persistent B fragments
    bf16x8 bw[4][8];
#pragma unroll
    for (int tu = 0; tu < 4; ++tu)
#pragma unroll
        for (int s = 0; s < 8; ++s) {
            const ushort* pp = Wl + ((size_t)((tu << 7) + u) << 8) + (s << 5) + (q << 3);
            bw[tu][s] = *(const bf16x8*)pp;
        }

    const float bv0 = bl[u];
    const float bv1 = bl[128 + u];
    const float bv2 = bl[256 + u];
    const float bv3 = bl[384 + u];

    f32x4 cc = {0.0f, 0.0f, 0.0f, 0.0f};

    // handoff thread map: row = tid>>5 (0..15), 4 consecutive u per thread
    const int crow = tid >> 5;
    const int cu4  = (tid & 31) << 2;
    // layer-0 staging map
    const int seg  = tid & 31;
    const bool act = (seg < 24);       // 24*4 = 96 cols

    uint2 xr = {0u, 0u};
    u64 hx = 0;
    int avail = 0;

    // preload step-0 input
    if (l == 0) {
        if (act) xr = *(const uint2*)(xb + (size_t)(b0 + crow) * 96 + (seg << 2));
    } else {
        avail = spin_ge(prog_up, (9 < T_) ? 9 : T_);
        hx = __hip_atomic_load((u64*)(ring_up + (size_t)(b0 + crow) * H_ + cu4),
                               __ATOMIC_RELAXED, __HIP_MEMORY_SCOPE_AGENT);
    }

    __syncthreads();   // LDS zero visible

    for (int t = 0; t < T_; ++t) {
        const int p = t & 1;

        // A: stage input for step t into comb[p] (h-part written by E(t-1))
        if (l == 0) {
            if (act) *(uint2*)&comb[p][crow][seg << 2] = xr;
        } else {
            *(u64*)&comb[p][crow][cu4] = hx;
        }

        __syncthreads();   // B: LDS visible; all prev-iter global ops drained

        // ---- C: global phase (issue everything, no forced waits) ----
        // C2: publish progress: h_{<=t-2} stores drained by barrier B(t-1)->B(t)
        if (tid == 0 && t >= 1)
            __hip_atomic_store(prog_self, t - 1, __ATOMIC_RELAXED, __HIP_MEMORY_SCOPE_AGENT);

        // C1: store h_{t-1} (sits in comb[p] h-part), coalesced [b][u]
        if (t >= 1) {
            u64 hold = *(const u64*)&comb[p][crow][kx + cu4];
            if (l < 3) {
                u64* dst = (u64*)(ring_self + (size_t)((t - 1) & (W_ - 1)) * RING_SLOT +
                                  (size_t)(b0 + crow) * H_ + cu4);
                __hip_atomic_store(dst, hold, __ATOMIC_RELAXED, __HIP_MEMORY_SCOPE_AGENT);
            } else {
                *(u64*)(h3 + (size_t)(t - 1) * RING_SLOT + (size_t)(b0 + crow) * H_ + cu4) = hold;
            }
        }

        // C3: producer back-pressure vs ring reuse (every 16 steps)
        if (l < 3 && t >= 32 && (t & 15) == 0)
            (void)spin_ge(prog_down, t - 17);

        // C4: prefetch input for step t+1
        if (t < T_ - 1) {
            if (l == 0) {
                if (act) xr = *(const uint2*)(xb + (size_t)((t + 1) * B_ + b0 + crow) * 96 + (seg << 2));
            } else {
                if (avail < t + 2) {
                    int tgt = t + 9; if (tgt > T_) tgt = T_;
                    avail = spin_ge(prog_up, tgt);
                }
                hx = __hip_atomic_load((u64*)(ring_up + (size_t)((t + 1) & (W_ - 1)) * RING_SLOT +
                                              (size_t)(b0 + crow) * H_ + cu4),
                                       __ATOMIC_RELAXED, __HIP_MEMORY_SCOPE_AGENT);
            }
        }

        // ---- D: gates = [x|h] . W^T  (M=16 rows, 4 gate tiles, K=256) ----
        f32x4 a0 = {bv0, bv0, bv0, bv0};
        f32x4 a1 = {bv1, bv1, bv1, bv1};
        f32x4 a2 = {bv2, bv2, bv2, bv2};
        f32x4 a3 = {bv3, bv3, bv3, bv3};
#pragma unroll
        for (int s = 0; s < 8; ++s) {
            bf16x8 av = *(const bf16x8*)&comb[p][lo][(s << 5) + (q << 3)];
            a0 = __builtin_amdgcn_mfma_f32_16x16x32_bf16(av, bw[0][s], a0, 0, 0, 0);
            a1 = __builtin_amdgcn_mfma_f32_16x16x32_bf16(av, bw[1][s], a1, 0, 0, 0);
            a2 = __builtin_amdgcn_mfma_f32_16x16x32_bf16(av, bw[2][s], a2, 0, 0, 0);
            a3 = __builtin_amdgcn_mfma_f32_16x16x32_bf16(av, bw[3][s], a3, 0, 0, 0);
        }

        // ---- E: cell update; h_t -> comb[p^1] (LDS only) ----
        // fused reciprocals: i*g = (1-eg)*rcp((1+ei)(1+eg));
        //                    o*tanh(c) = (1-ec)*rcp((1+eo)(1+ec))
        // exp2 args clamped at 60 so products stay < 2^121 (no inf*0 NaN).
#pragma unroll
        for (int r = 0; r < 4; ++r) {
            float ei = exp2_fast(fminf(-a0[r], 60.0f));
            float ef = exp2_fast(-a1[r]);                 // graceful: rcp(inf)=0
            float eg = exp2_fast(fminf(-a2[r], 60.0f));
            float eo = exp2_fast(fminf(-a3[r], 60.0f));
            float rf  = rcp_fast(1.0f + ef);
            float rig = rcp_fast((1.0f + ei) * (1.0f + eg));
            float cn  = __builtin_fmaf(cc[r], rf, (1.0f - eg) * rig);
            cc[r] = cn;
            float ec  = exp2_fast(fminf(-2.88539008177793f * cn, 60.0f));
            float roc = rcp_fast((1.0f + eo) * (1.0f + ec));
            float h_  = (1.0f - ec) * roc;
            comb[p ^ 1][(q << 2) + r][kx + u] = bf16_rn(h_);
        }
    }

    // post-loop: store h_{T-1} (in comb[T_&1]) and final publish
    __syncthreads();
    {
        u64 hold = *(const u64*)&comb[T_ & 1][crow][kx + cu4];
        if (l < 3) {
            u64* dst = (u64*)(ring_self + (size_t)((T_ - 1) & (W_ - 1)) * RING_SLOT +
                              (size_t)(b0 + crow) * H_ + cu4);
            __hip_atomic_store(dst, hold, __ATOMIC_RELAXED, __HIP_MEMORY_SCOPE_AGENT);
        } else {
            *(u64*)(h3 + (size_t)(T_ - 1) * RING_SLOT + (size_t)(b0 + crow) * H_ + cu4) = hold;
        }
    }
    __syncthreads();   // each thread's stores drained before its barrier entry
    if (tid == 0)
        __hip_atomic_store(prog_self, T_, __ATOMIC_RELAXED, __HIP_MEMORY_SCOPE_AGENT);
}

// ---------------------------------------------------------------------------
// fc: out[b*T+t] = sigmoid( dot(h3[t][b][:], wfc) + bfc ); h3 layout [t][b][u]
// ---------------------------------------------------------------------------
__global__ void fc_kernel(const ushort* __restrict__ h3,
                          const float* __restrict__ wfc,
                          const float* __restrict__ bfc,
                          float* __restrict__ out) {
    int t = blockIdx.x;
    int b = threadIdx.x;
    const uint4* hp = (const uint4*)(h3 + ((size_t)t * B_ + b) * H_);
    float acc = 0.0f;
#pragma unroll
    for (int kk = 0; kk < 16; ++kk) {
        uint4 pv = hp[kk];
        const uint vv[4] = {pv.x, pv.y, pv.z, pv.w};
#pragma unroll
        for (int j = 0; j < 4; ++j) {
            float f0 = __uint_as_float(vv[j] << 16);
            float f1 = __uint_as_float(vv[j] & 0xFFFF0000u);
            acc = __builtin_fmaf(f0, wfc[kk * 8 + j * 2 + 0], acc);
            acc = __builtin_fmaf(f1, wfc[kk * 8 + j * 2 + 1], acc);
        }
    }
    float z = acc + bfc[0];
    out[(size_t)b * T_ + t] = rcp_fast(1.0f + exp2_fast(-z * LOG2E));
}

// ---------------------------------------------------------------------------
extern "C" void kernel_launch(void* const* d_in, const int* in_sizes, int n_in,
                              void* d_out, int out_size, void* d_ws, size_t ws_size,
                              hipStream_t stream) {
    const float* x    = (const float*)d_in[0];
    const float* Wih0 = (const float*)d_in[1];
    const float* Wihr = (const float*)d_in[2];
    const float* Whh  = (const float*)d_in[3];
    const float* bih  = (const float*)d_in[4];
    const float* bhh  = (const float*)d_in[5];
    const float* Wfc  = (const float*)d_in[6];
    const float* bfc  = (const float*)d_in[7];
    float* out = (float*)d_out;

    char* ws = (char*)d_ws;
    const size_t xb_bytes   = (size_t)T_ * B_ * 96 * 2;           // 25,165,824
    const size_t wc_bytes   = (size_t)NL_ * G_ * 256 * 2;         //  1,048,576
    const size_t bias_bytes = (size_t)NL_ * G_ * 4;               //      8,192
    const size_t prog_bytes = (size_t)NL_ * 16 * 16 * 4;          //      4,096
    const size_t ring_bytes = (size_t)3 * RING_L * 2;             //  6,291,456

    ushort* xb    = (ushort*)ws;
    ushort* Wc    = (ushort*)(ws + xb_bytes);
    float*  biasc = (float*)(ws + xb_bytes + wc_bytes);
    int*    prog  = (int*)(ws + xb_bytes + wc_bytes + bias_bytes);
    ushort* ring  = (ushort*)(ws + xb_bytes + wc_bytes + bias_bytes + prog_bytes);
    ushort* h3    = (ushort*)(ws + xb_bytes + wc_bytes + bias_bytes + prog_bytes + ring_bytes);

    prep_x<<<(T_ * B_ * 96) / 256, 256, 0, stream>>>(x, xb);
    prep_w<<<(NL_ * G_ * 256) / 256, 256, 0, stream>>>(Wih0, Wihr, Whh, Wc);
    prep_bias<<<(NL_ * G_) / 256, 256, 0, stream>>>(bih, bhh, biasc);
    zero_prog<<<1, 256, 0, stream>>>(prog);

    recur_all<<<NL_ * 16, 512, 0, stream>>>(xb, Wc, biasc, ring, h3, prog);

    fc_kernel<<<T_, B_, 0, stream>>>(h3, Wfc, bfc, out);
}